// Round 1
// baseline (599.532 us; speedup 1.0000x reference)
//
#include <hip/hip_runtime.h>

#define N 8192
#define FIN 128
#define FOUT 64
#define ALPHA 0.2f
#define MI 8

static __device__ __forceinline__ float bcast(float v, int l) {
    return __int_as_float(__builtin_amdgcn_readlane(__float_as_int(v), l));
}

// Wh[r][c] = sum_k h[r][k] W[k][c];  s[r] = Wh[r,:]·a[:64];  t[r] = Wh[r,:]·a[64:]
__global__ __launch_bounds__(256) void k_prep(const float* __restrict__ h,
                                              const float* __restrict__ W,
                                              const float* __restrict__ a,
                                              float* __restrict__ Wh,
                                              float* __restrict__ s,
                                              float* __restrict__ t) {
    int wave = threadIdx.x >> 6;
    int lane = threadIdx.x & 63;
    int r = (blockIdx.x << 2) + wave;
    const float* hr = h + (size_t)r * FIN;
    float acc = 0.f;
#pragma unroll
    for (int k = 0; k < FIN; ++k) acc = fmaf(hr[k], W[k * FOUT + lane], acc);
    Wh[(size_t)r * FOUT + lane] = acc;
    float sv = acc * a[lane];
    float tv = acc * a[FOUT + lane];
#pragma unroll
    for (int off = 32; off; off >>= 1) {
        sv += __shfl_xor(sv, off);
        tv += __shfl_xor(tv, off);
    }
    if (lane == 0) { s[r] = sv; t[r] = tv; }
}

// m = leakyrelu(max(s) + max(t)) — a global upper bound on all e_ij (monotonicity)
__global__ __launch_bounds__(256) void k_max(const float* __restrict__ s,
                                             const float* __restrict__ t,
                                             float* __restrict__ m) {
    __shared__ float rs[4], rt[4];
    int lane = threadIdx.x & 63, wave = threadIdx.x >> 6;
    float ms = -1e30f, mt = -1e30f;
    for (int i = threadIdx.x; i < N; i += 256) {
        ms = fmaxf(ms, s[i]);
        mt = fmaxf(mt, t[i]);
    }
#pragma unroll
    for (int off = 32; off; off >>= 1) {
        ms = fmaxf(ms, __shfl_xor(ms, off));
        mt = fmaxf(mt, __shfl_xor(mt, off));
    }
    if (lane == 0) { rs[wave] = ms; rt[wave] = mt; }
    __syncthreads();
    if (threadIdx.x == 0) {
        float a1 = fmaxf(fmaxf(rs[0], rs[1]), fmaxf(rs[2], rs[3]));
        float a2 = fmaxf(fmaxf(rt[0], rt[1]), fmaxf(rt[2], rt[3]));
        float e = a1 + a2;
        m[0] = e > 0.f ? e : ALPHA * e;
    }
}

// Fused: p_ij = adj_ij * exp(leakyrelu(s_i + t_j) - m); out_i = elu( (Σ p Wh) / Σ p )
// Wave layout: lane = output column c. Each wave owns MI=8 rows and half the j range.
// Wave pairs (jh=0/1) split j and combine via LDS. adj/t prefetched one chunk ahead.
__global__ __launch_bounds__(256) void k_attn(const float* __restrict__ adj,
                                              const float* __restrict__ Wh,
                                              const float* __restrict__ s,
                                              const float* __restrict__ t,
                                              const float* __restrict__ mp,
                                              float* __restrict__ out) {
    __shared__ float sh_acc[2][MI][FOUT];
    __shared__ float sh_l[2][MI];
    int wave = threadIdx.x >> 6;
    int lane = threadIdx.x & 63;
    int rg = wave >> 1;  // row group within block (0/1)
    int jh = wave & 1;   // j half (0/1)
    int i0 = blockIdx.x * (2 * MI) + rg * MI;
    float m = mp[0];
    float sv[MI];
#pragma unroll
    for (int r = 0; r < MI; ++r) sv[r] = s[i0 + r];
    float acc[MI], lsum[MI];
#pragma unroll
    for (int r = 0; r < MI; ++r) { acc[r] = 0.f; lsum[r] = 0.f; }

    const int jbeg = jh * (N / 2);
    const int jend = jbeg + (N / 2);

    // prefetch first chunk
    float av[MI], tv;
    tv = t[jbeg + lane];
#pragma unroll
    for (int r = 0; r < MI; ++r) av[r] = adj[(size_t)(i0 + r) * N + jbeg + lane];

    for (int j0 = jbeg; j0 < jend; j0 += 64) {
        // p for this chunk (lanes = 64 j's, fully utilized exp)
        float p[MI];
#pragma unroll
        for (int r = 0; r < MI; ++r) {
            float e = sv[r] + tv;
            float le = e > 0.f ? e : ALPHA * e;
            float pv = av[r] * __expf(le - m);
            p[r] = pv;
            lsum[r] += pv;
        }
        // prefetch next chunk (HBM latency hidden under broadcast loop)
        int jn = j0 + 64;
        if (jn < jend) {
            tv = t[jn + lane];
#pragma unroll
            for (int r = 0; r < MI; ++r) av[r] = adj[(size_t)(i0 + r) * N + jn + lane];
        }
        // rank-64 update: acc[r][c] += p[r][jj] * Wh[j0+jj][c]
#pragma unroll
        for (int jj = 0; jj < 64; ++jj) {
            float whc = Wh[(size_t)(j0 + jj) * FOUT + lane];
#pragma unroll
            for (int r = 0; r < MI; ++r) {
                acc[r] = fmaf(bcast(p[r], jj), whc, acc[r]);
            }
        }
    }

    // reduce lsum across lanes (each lane summed its own jj's)
#pragma unroll
    for (int r = 0; r < MI; ++r) {
        float v = lsum[r];
#pragma unroll
        for (int off = 32; off; off >>= 1) v += __shfl_xor(v, off);
        lsum[r] = v;
    }

    // combine the two j-halves
    if (jh == 1) {
#pragma unroll
        for (int r = 0; r < MI; ++r) sh_acc[rg][r][lane] = acc[r];
        if (lane == 0) {
#pragma unroll
            for (int r = 0; r < MI; ++r) sh_l[rg][r] = lsum[r];
        }
    }
    __syncthreads();
    if (jh == 0) {
#pragma unroll
        for (int r = 0; r < MI; ++r) {
            float tot = acc[r] + sh_acc[rg][r][lane];
            float l = lsum[r] + sh_l[rg][r];
            float v = tot / l;
            out[(size_t)(i0 + r) * FOUT + lane] = v > 0.f ? v : (__expf(v) - 1.f);
        }
    }
}

extern "C" void kernel_launch(void* const* d_in, const int* in_sizes, int n_in,
                              void* d_out, int out_size, void* d_ws, size_t ws_size,
                              hipStream_t stream) {
    const float* h   = (const float*)d_in[0];
    const float* adj = (const float*)d_in[1];
    const float* W   = (const float*)d_in[2];
    const float* a   = (const float*)d_in[3];
    float* out = (float*)d_out;

    // ws layout: Wh (N*FOUT f32 = 2 MB) | s (N) | t (N) | m (1)  => ~2.07 MB total
    float* Wh = (float*)d_ws;
    float* s  = Wh + (size_t)N * FOUT;
    float* t  = s + N;
    float* m  = t + N;

    k_prep<<<N / 4, 256, 0, stream>>>(h, W, a, Wh, s, t);
    k_max<<<1, 256, 0, stream>>>(s, t, m);
    k_attn<<<N / (2 * MI), 256, 0, stream>>>(adj, Wh, s, t, m, out);
}

// Round 2
// 427.076 us; speedup vs baseline: 1.4038x; 1.4038x over previous
//
#include <hip/hip_runtime.h>
#include <hip/hip_bf16.h>

#define N 8192
#define FIN 128
#define FOUT 64
#define ALPHA 0.2f
#define LOG2E 1.44269504f
#define JPW (N / 8)   // j-range per wave in k_attn (8 waves/block)

typedef __attribute__((ext_vector_type(8))) short short8;
typedef __attribute__((ext_vector_type(4))) float f32x4;

static __device__ __forceinline__ unsigned fkey(float x) {
    unsigned u = __float_as_uint(x);
    return (u >> 31) ? ~u : (u | 0x80000000u);
}
static __device__ __forceinline__ float fdecode(unsigned k) {
    unsigned u = (k & 0x80000000u) ? (k & 0x7FFFFFFFu) : ~k;
    return __uint_as_float(u);
}

// ---------------- k_prep: Wh = h@W (fp32), s = Wh@a1, t = Wh@a2, global max keys ----
__global__ __launch_bounds__(256) void k_prep(const float* __restrict__ h,
                                              const float* __restrict__ W,
                                              const float* __restrict__ a,
                                              float* __restrict__ Wh,
                                              float* __restrict__ s,
                                              float* __restrict__ t,
                                              unsigned* __restrict__ keys) {
    __shared__ float lH[16 * FIN];    // 8 KB
    __shared__ float lW[FIN * FOUT];  // 32 KB
    __shared__ float red[8];
    const int tid = threadIdx.x;
    const int r0 = blockIdx.x * 16;
    {   // coalesced float4 staging
        const float4* src = (const float4*)(h + (size_t)r0 * FIN);
        float4* dst = (float4*)lH;
        for (int i = tid; i < 16 * FIN / 4; i += 256) dst[i] = src[i];
        const float4* ws_ = (const float4*)W;
        float4* dw = (float4*)lW;
        for (int i = tid; i < FIN * FOUT / 4; i += 256) dw[i] = ws_[i];
    }
    __syncthreads();
    const int wave = tid >> 6, lane = tid & 63;
    float acc[4] = {0.f, 0.f, 0.f, 0.f};
    for (int k = 0; k < FIN; ++k) {
        float wv = lW[k * FOUT + lane];
#pragma unroll
        for (int r = 0; r < 4; ++r)
            acc[r] = fmaf(lH[(wave * 4 + r) * FIN + k], wv, acc[r]);
    }
    const float a1 = a[lane], a2 = a[FOUT + lane];
    float smx = -1e30f, tmx = -1e30f;
#pragma unroll
    for (int r = 0; r < 4; ++r) {
        int row = r0 + wave * 4 + r;
        Wh[(size_t)row * FOUT + lane] = acc[r];
        float sv = acc[r] * a1, tv = acc[r] * a2;
#pragma unroll
        for (int off = 32; off; off >>= 1) {
            sv += __shfl_xor(sv, off);
            tv += __shfl_xor(tv, off);
        }
        if (lane == 0) { s[row] = sv; t[row] = tv; }
        smx = fmaxf(smx, sv);  // shfl_xor chain leaves full sum on every lane
        tmx = fmaxf(tmx, tv);
    }
    if (lane == 0) { red[wave] = smx; red[4 + wave] = tmx; }
    __syncthreads();
    if (tid == 0) {
        float ms = fmaxf(fmaxf(red[0], red[1]), fmaxf(red[2], red[3]));
        float mt = fmaxf(fmaxf(red[4], red[5]), fmaxf(red[6], red[7]));
        atomicMax(keys + 0, fkey(ms));   // one atomic per block: low contention
        atomicMax(keys + 1, fkey(mt));
    }
}

// ---------------- k_pack: Wh fp32 -> bf16 B-fragment layout ------------------------
// B-frag (16x16x32): lane holds col n = lane&15, k = (lane>>4)*8 + e, e=0..7
// WhB[((chunk*4 + tile)*64 + lane)*8 + e] = bf16(Wh[chunk*32 + (lane>>4)*8 + e][tile*16 + (lane&15)])
__global__ __launch_bounds__(256) void k_pack(const float* __restrict__ Wh,
                                              __hip_bfloat16* __restrict__ WhB) {
    const int c = blockIdx.x;            // k-chunk 0..255
    const int tn = threadIdx.x >> 6;     // col tile 0..3
    const int lane = threadIdx.x & 63;
    const int quad = lane >> 4, l16 = lane & 15;
    const float* src = Wh + ((size_t)(c * 32 + quad * 8)) * FOUT + tn * 16 + l16;
    union { unsigned short u[8]; short8 v; } frag;
#pragma unroll
    for (int e = 0; e < 8; ++e) {
        __hip_bfloat16 b = __float2bfloat16(src[(size_t)e * FOUT]);
        frag.u[e] = *(unsigned short*)&b;
    }
    *(short8*)&WhB[(((size_t)c * 4 + tn) * 64 + lane) * 8] = frag.v;
}

// ---------------- k_attn: fused mask+softmax+PV via MFMA ---------------------------
// Block: 512 thr = 8 waves; block owns 16 rows; wave w covers j in [w*1024, (w+1)*1024).
// Unit = 32 j (one K-step). A-frag: lane row m=lane&15, k=(lane>>4)*8+e.
__global__ __launch_bounds__(512, 4) void k_attn(const float* __restrict__ adj,
                                                 const __hip_bfloat16* __restrict__ WhB,
                                                 const float* __restrict__ s,
                                                 const float* __restrict__ t,
                                                 const unsigned* __restrict__ keys,
                                                 float* __restrict__ out) {
    __shared__ float shacc[8][4][64][4];  // 32 KB [wave][tile][lane][reg]
    __shared__ float shl[8][16];
    const int wave = threadIdx.x >> 6, lane = threadIdx.x & 63;
    const int quad = lane >> 4, l16 = lane & 15;
    const int i0 = blockIdx.x * 16;

    const float mraw = fdecode(keys[0]) + fdecode(keys[1]);
    const float mle = mraw > 0.f ? mraw : ALPHA * mraw;  // bound on leakyrelu(e)
    const float mm = mle * LOG2E;
    const float sm = s[i0 + l16];

    const float* arow = adj + (size_t)(i0 + l16) * N + wave * JPW + quad * 8;
    const float* trow = t + wave * JPW + quad * 8;
    const short8* BF = (const short8*)WhB;

    f32x4 acc0 = {0,0,0,0}, acc1 = {0,0,0,0}, acc2 = {0,0,0,0}, acc3 = {0,0,0,0};
    float lsum = 0.f;

    float4 ca0, ca1, ct0, ct1, na0, na1, nt0, nt1;
    ca0 = *(const float4*)(arow);     ca1 = *(const float4*)(arow + 4);
    ct0 = *(const float4*)(trow);     ct1 = *(const float4*)(trow + 4);

    const int UNITS = JPW / 32;  // 32
#pragma unroll 4
    for (int u = 0; u < UNITS; ++u) {
        // prefetch next unit's adj + t (HBM latency hidden under compute)
        if (u + 1 < UNITS) {
            const float* an = arow + (u + 1) * 32;
            const float* tn_ = trow + (u + 1) * 32;
            na0 = *(const float4*)(an);      na1 = *(const float4*)(an + 4);
            nt0 = *(const float4*)(tn_);     nt1 = *(const float4*)(tn_ + 4);
        }
        // B fragments for this K-chunk (L2-resident, coalesced b128)
        const size_t cidx = (size_t)(wave * UNITS + u) * 4;
        short8 b0 = BF[(cidx + 0) * 64 + lane];
        short8 b1 = BF[(cidx + 1) * 64 + lane];
        short8 b2 = BF[(cidx + 2) * 64 + lane];
        short8 b3 = BF[(cidx + 3) * 64 + lane];

        // p = adj * exp(leakyrelu(s_i + t_j) - mle), rounded to bf16 (consistent num/denom)
        union { unsigned short u16[8]; short8 v; } af;
        const float* ap = (const float*)&ca0;
        const float* tp = (const float*)&ct0;
#pragma unroll
        for (int e = 0; e < 8; ++e) {
            float av = (e < 4) ? ap[e] : ((const float*)&ca1)[e - 4];
            float tv = (e < 4) ? tp[e] : ((const float*)&ct1)[e - 4];
            float x = sm + tv;
            float le = fmaxf(x, ALPHA * x);
            float ex = exp2f(fmaf(le, LOG2E, -mm));
            float p = av * ex;
            __hip_bfloat16 pb = __float2bfloat16(p);
            unsigned short ub = *(unsigned short*)&pb;
            af.u16[e] = ub;
            lsum += __uint_as_float(((unsigned)ub) << 16);
        }
        ca0 = na0; ca1 = na1; ct0 = nt0; ct1 = nt1;

        acc0 = __builtin_amdgcn_mfma_f32_16x16x32_bf16(af.v, b0, acc0, 0, 0, 0);
        acc1 = __builtin_amdgcn_mfma_f32_16x16x32_bf16(af.v, b1, acc1, 0, 0, 0);
        acc2 = __builtin_amdgcn_mfma_f32_16x16x32_bf16(af.v, b2, acc2, 0, 0, 0);
        acc3 = __builtin_amdgcn_mfma_f32_16x16x32_bf16(af.v, b3, acc3, 0, 0, 0);
    }

    // row-sum of p across the wave: lanes {m, m+16, m+32, m+48} hold row m partials
    lsum += __shfl_xor(lsum, 16);
    lsum += __shfl_xor(lsum, 32);

    // stash per-wave partials
#pragma unroll
    for (int r = 0; r < 4; ++r) {
        shacc[wave][0][lane][r] = acc0[r];
        shacc[wave][1][lane][r] = acc1[r];
        shacc[wave][2][lane][r] = acc2[r];
        shacc[wave][3][lane][r] = acc3[r];
    }
    if (lane < 16) shl[wave][lane] = lsum;
    __syncthreads();

    if (wave == 4 && lane < 16) {  // combine row sums
        float v = 0.f;
#pragma unroll
        for (int w = 0; w < 8; ++w) v += shl[w][lane];
        shl[0][lane] = v;
    }
    float tot[4] = {0.f, 0.f, 0.f, 0.f};
    if (wave < 4) {  // wave w reduces + outputs col-tile w
#pragma unroll
        for (int w = 0; w < 8; ++w) {
            float4 c = *(const float4*)&shacc[w][wave][lane][0];
#pragma unroll
            for (int r = 0; r < 4; ++r) tot[r] += ((const float*)&c)[r];
        }
    }
    __syncthreads();
    if (wave < 4) {
#pragma unroll
        for (int r = 0; r < 4; ++r) {
            int row = quad * 4 + r;                      // C/D: row=(lane>>4)*4+reg
            float l = shl[0][row];
            float v = tot[r] / l;
            float o = v > 0.f ? v : (exp2f(v * LOG2E) - 1.f);
            out[(size_t)(i0 + row) * FOUT + wave * 16 + l16] = o;
        }
    }
}

extern "C" void kernel_launch(void* const* d_in, const int* in_sizes, int n_in,
                              void* d_out, int out_size, void* d_ws, size_t ws_size,
                              hipStream_t stream) {
    const float* h   = (const float*)d_in[0];
    const float* adj = (const float*)d_in[1];
    const float* W   = (const float*)d_in[2];
    const float* a   = (const float*)d_in[3];
    float* out = (float*)d_out;

    // ws: Wh fp32 (2 MB) | WhB bf16 (1 MB) | s (32 KB) | t (32 KB) | keys (8 B)
    float* Wh = (float*)d_ws;
    __hip_bfloat16* WhB = (__hip_bfloat16*)(Wh + (size_t)N * FOUT);
    float* s = (float*)(WhB + (size_t)N * FOUT);
    float* t = s + N;
    unsigned* keys = (unsigned*)(t + N);

    hipMemsetAsync(keys, 0, 2 * sizeof(unsigned), stream);
    k_prep<<<N / 16, 256, 0, stream>>>(h, W, a, Wh, s, t, keys);
    k_pack<<<N / 32, 256, 0, stream>>>(Wh, WhB);
    k_attn<<<N / 16, 512, 0, stream>>>(adj, WhB, s, t, keys, out);
}

// Round 3
// 424.240 us; speedup vs baseline: 1.4132x; 1.0067x over previous
//
#include <hip/hip_runtime.h>
#include <hip/hip_bf16.h>

#define N 8192
#define FIN 128
#define FOUT 64
#define ALPHA 0.2f
#define LOG2E 1.44269504f
#define JPW (N / 8)       // j-range per wave in k_attn (8 waves/block)
#define UNITS (JPW / 32)  // 32 K-steps of 32 j each

typedef __attribute__((ext_vector_type(8))) short short8;
typedef __attribute__((ext_vector_type(4))) float f32x4;

static __device__ __forceinline__ unsigned fkey(float x) {
    unsigned u = __float_as_uint(x);
    return (u >> 31) ? ~u : (u | 0x80000000u);
}
static __device__ __forceinline__ float fdecode(unsigned k) {
    unsigned u = (k & 0x80000000u) ? (k & 0x7FFFFFFFu) : ~k;
    return __uint_as_float(u);
}

// ---------------- k_prep: Wh = h@W (fp32), s = Wh@a1, t = Wh@a2, global max keys ----
__global__ __launch_bounds__(256) void k_prep(const float* __restrict__ h,
                                              const float* __restrict__ W,
                                              const float* __restrict__ a,
                                              float* __restrict__ Wh,
                                              float* __restrict__ s,
                                              float* __restrict__ t,
                                              unsigned* __restrict__ keys) {
    __shared__ float lH[16 * FIN];    // 8 KB
    __shared__ float lW[FIN * FOUT];  // 32 KB
    __shared__ float red[8];
    const int tid = threadIdx.x;
    const int r0 = blockIdx.x * 16;
    {   // coalesced float4 staging
        const float4* src = (const float4*)(h + (size_t)r0 * FIN);
        float4* dst = (float4*)lH;
        for (int i = tid; i < 16 * FIN / 4; i += 256) dst[i] = src[i];
        const float4* ws_ = (const float4*)W;
        float4* dw = (float4*)lW;
        for (int i = tid; i < FIN * FOUT / 4; i += 256) dw[i] = ws_[i];
    }
    __syncthreads();
    const int wave = tid >> 6, lane = tid & 63;
    float acc[4] = {0.f, 0.f, 0.f, 0.f};
    for (int k = 0; k < FIN; ++k) {
        float wv = lW[k * FOUT + lane];
#pragma unroll
        for (int r = 0; r < 4; ++r)
            acc[r] = fmaf(lH[(wave * 4 + r) * FIN + k], wv, acc[r]);
    }
    const float a1 = a[lane], a2 = a[FOUT + lane];
    float smx = -1e30f, tmx = -1e30f;
#pragma unroll
    for (int r = 0; r < 4; ++r) {
        int row = r0 + wave * 4 + r;
        Wh[(size_t)row * FOUT + lane] = acc[r];
        float sv = acc[r] * a1, tv = acc[r] * a2;
#pragma unroll
        for (int off = 32; off; off >>= 1) {
            sv += __shfl_xor(sv, off);
            tv += __shfl_xor(tv, off);
        }
        if (lane == 0) { s[row] = sv; t[row] = tv; }
        smx = fmaxf(smx, sv);  // shfl_xor chain leaves full sum on every lane
        tmx = fmaxf(tmx, tv);
    }
    if (lane == 0) { red[wave] = smx; red[4 + wave] = tmx; }
    __syncthreads();
    if (tid == 0) {
        float ms = fmaxf(fmaxf(red[0], red[1]), fmaxf(red[2], red[3]));
        float mt = fmaxf(fmaxf(red[4], red[5]), fmaxf(red[6], red[7]));
        atomicMax(keys + 0, fkey(ms));   // one atomic per block: low contention
        atomicMax(keys + 1, fkey(mt));
    }
}

// ---------------- k_pack: Wh fp32 -> bf16 B-fragment layout ------------------------
// B-frag (16x16x32): lane holds col n = lane&15, k = (lane>>4)*8 + e, e=0..7
__global__ __launch_bounds__(256) void k_pack(const float* __restrict__ Wh,
                                              __hip_bfloat16* __restrict__ WhB) {
    const int c = blockIdx.x;            // k-chunk 0..255
    const int tn = threadIdx.x >> 6;     // col tile 0..3
    const int lane = threadIdx.x & 63;
    const int quad = lane >> 4, l16 = lane & 15;
    const float* src = Wh + ((size_t)(c * 32 + quad * 8)) * FOUT + tn * 16 + l16;
    union { unsigned short u[8]; short8 v; } frag;
#pragma unroll
    for (int e = 0; e < 8; ++e) {
        __hip_bfloat16 b = __float2bfloat16(src[(size_t)e * FOUT]);
        frag.u[e] = *(unsigned short*)&b;
    }
    *(short8*)&WhB[(((size_t)c * 4 + tn) * 64 + lane) * 8] = frag.v;
}

// ---------------- k_attn: fused mask+softmax+PV via MFMA, 2-stage SW pipeline ------
struct Unit {
    float4 a0, a1;   // adj: 8 floats/lane (rows = l16, k = quad*8+e)
    float4 t0, t1;   // t_j for the same 8 k's
    short8 b0, b1, b2, b3;  // B fragments, 4 col-tiles
};

static __device__ __forceinline__ void load_unit(Unit& U, const float* __restrict__ arow,
                                                 const float* __restrict__ trow,
                                                 const short8* __restrict__ BF,
                                                 int wave, int lane, int u) {
    const float* ap = arow + u * 32;
    const float* tp = trow + u * 32;
    U.a0 = *(const float4*)ap;       U.a1 = *(const float4*)(ap + 4);
    U.t0 = *(const float4*)tp;       U.t1 = *(const float4*)(tp + 4);
    const size_t cidx = ((size_t)(wave * UNITS + u)) * 4;
    U.b0 = BF[(cidx + 0) * 64 + lane];
    U.b1 = BF[(cidx + 1) * 64 + lane];
    U.b2 = BF[(cidx + 2) * 64 + lane];
    U.b3 = BF[(cidx + 3) * 64 + lane];
}

static __device__ __forceinline__ void proc_unit(const Unit& U, float sm, float mm,
                                                 f32x4& acc0, f32x4& acc1,
                                                 f32x4& acc2, f32x4& acc3,
                                                 float& lsum) {
    union { unsigned short u16[8]; short8 v; } af;
    const float* ap0 = (const float*)&U.a0;
    const float* ap1 = (const float*)&U.a1;
    const float* tp0 = (const float*)&U.t0;
    const float* tp1 = (const float*)&U.t1;
#pragma unroll
    for (int e = 0; e < 8; ++e) {
        float av = (e < 4) ? ap0[e] : ap1[e - 4];
        float tv = (e < 4) ? tp0[e] : tp1[e - 4];
        float x = sm + tv;
        float le = fmaxf(x, ALPHA * x);
        float ex = exp2f(fmaf(le, LOG2E, -mm));
        float p = av * ex;
        __hip_bfloat16 pb = __float2bfloat16(p);
        unsigned short ub = *(unsigned short*)&pb;
        af.u16[e] = ub;
        lsum += __uint_as_float(((unsigned)ub) << 16);  // consistent num/denom
    }
    acc0 = __builtin_amdgcn_mfma_f32_16x16x32_bf16(af.v, U.b0, acc0, 0, 0, 0);
    acc1 = __builtin_amdgcn_mfma_f32_16x16x32_bf16(af.v, U.b1, acc1, 0, 0, 0);
    acc2 = __builtin_amdgcn_mfma_f32_16x16x32_bf16(af.v, U.b2, acc2, 0, 0, 0);
    acc3 = __builtin_amdgcn_mfma_f32_16x16x32_bf16(af.v, U.b3, acc3, 0, 0, 0);
}

// Block: 512 thr = 8 waves; block owns 16 rows; wave w covers j in [w*1024,(w+1)*1024)
__global__ __launch_bounds__(512, 4) void k_attn(const float* __restrict__ adj,
                                                 const __hip_bfloat16* __restrict__ WhB,
                                                 const float* __restrict__ s,
                                                 const float* __restrict__ t,
                                                 const unsigned* __restrict__ keys,
                                                 float* __restrict__ out) {
    __shared__ float shacc[8][4][64][4];  // 32 KB [wave][tile][lane][reg]
    __shared__ float shl[8][16];
    const int wave = threadIdx.x >> 6, lane = threadIdx.x & 63;
    const int quad = lane >> 4, l16 = lane & 15;
    const int i0 = blockIdx.x * 16;

    const float mraw = fdecode(keys[0]) + fdecode(keys[1]);
    const float mle = mraw > 0.f ? mraw : ALPHA * mraw;  // bound on leakyrelu(e)
    const float mm = mle * LOG2E;
    const float sm = s[i0 + l16];

    const float* arow = adj + (size_t)(i0 + l16) * N + wave * JPW + quad * 8;
    const float* trow = t + wave * JPW + quad * 8;
    const short8* BF = (const short8*)WhB;

    f32x4 acc0 = {0,0,0,0}, acc1 = {0,0,0,0}, acc2 = {0,0,0,0}, acc3 = {0,0,0,0};
    float lsum = 0.f;

    // 2-stage register pipeline: consume a buffer, then refill it for u+2.
    Unit S0, S1;
    load_unit(S0, arow, trow, BF, wave, lane, 0);
    load_unit(S1, arow, trow, BF, wave, lane, 1);
    for (int u = 0; u < UNITS - 2; u += 2) {
        proc_unit(S0, sm, mm, acc0, acc1, acc2, acc3, lsum);
        load_unit(S0, arow, trow, BF, wave, lane, u + 2);
        proc_unit(S1, sm, mm, acc0, acc1, acc2, acc3, lsum);
        load_unit(S1, arow, trow, BF, wave, lane, u + 3);
    }
    proc_unit(S0, sm, mm, acc0, acc1, acc2, acc3, lsum);  // unit 30
    proc_unit(S1, sm, mm, acc0, acc1, acc2, acc3, lsum);  // unit 31

    // row-sum of p across the wave: lanes {m, m+16, m+32, m+48} hold row m partials
    lsum += __shfl_xor(lsum, 16);
    lsum += __shfl_xor(lsum, 32);

    // stash per-wave partials
#pragma unroll
    for (int r = 0; r < 4; ++r) {
        shacc[wave][0][lane][r] = acc0[r];
        shacc[wave][1][lane][r] = acc1[r];
        shacc[wave][2][lane][r] = acc2[r];
        shacc[wave][3][lane][r] = acc3[r];
    }
    if (lane < 16) shl[wave][lane] = lsum;
    __syncthreads();

    if (wave == 4 && lane < 16) {  // combine row sums
        float v = 0.f;
#pragma unroll
        for (int w = 0; w < 8; ++w) v += shl[w][lane];
        shl[0][lane] = v;
    }
    float tot[4] = {0.f, 0.f, 0.f, 0.f};
    if (wave < 4) {  // wave w reduces + outputs col-tile w
#pragma unroll
        for (int w = 0; w < 8; ++w) {
            float4 c = *(const float4*)&shacc[w][wave][lane][0];
#pragma unroll
            for (int r = 0; r < 4; ++r) tot[r] += ((const float*)&c)[r];
        }
    }
    __syncthreads();
    if (wave < 4) {
#pragma unroll
        for (int r = 0; r < 4; ++r) {
            int row = quad * 4 + r;                      // C/D: row=(lane>>4)*4+reg
            float l = shl[0][row];
            float v = tot[r] / l;
            float o = v > 0.f ? v : (exp2f(v * LOG2E) - 1.f);
            out[(size_t)(i0 + row) * FOUT + wave * 16 + l16] = o;
        }
    }
}

extern "C" void kernel_launch(void* const* d_in, const int* in_sizes, int n_in,
                              void* d_out, int out_size, void* d_ws, size_t ws_size,
                              hipStream_t stream) {
    const float* h   = (const float*)d_in[0];
    const float* adj = (const float*)d_in[1];
    const float* W   = (const float*)d_in[2];
    const float* a   = (const float*)d_in[3];
    float* out = (float*)d_out;

    // ws: Wh fp32 (2 MB) | WhB bf16 (1 MB) | s (32 KB) | t (32 KB) | keys (8 B)
    float* Wh = (float*)d_ws;
    __hip_bfloat16* WhB = (__hip_bfloat16*)(Wh + (size_t)N * FOUT);
    float* s = (float*)(WhB + (size_t)N * FOUT);
    float* t = s + N;
    unsigned* keys = (unsigned*)(t + N);

    hipMemsetAsync(keys, 0, 2 * sizeof(unsigned), stream);
    k_prep<<<N / 16, 256, 0, stream>>>(h, W, a, Wh, s, t, keys);
    k_pack<<<N / 32, 256, 0, stream>>>(Wh, WhB);
    k_attn<<<N / 16, 512, 0, stream>>>(adj, WhB, s, t, keys, out);
}